// Round 1
// baseline (613.891 us; speedup 1.0000x reference)
//
#include <hip/hip_runtime.h>
#include <cstdint>
#include <cstddef>

#define LOG2E 1.4426950408889634f

constexpr int Dm  = 192;
constexpr int DEe = 96;
constexpr int Hh  = 8;
constexpr int DHh = 24;

enum { M_NONE = 0, M_BIAS = 1, M_SILU = 2, M_GATE_LN = 3, M_RES_LN = 4 };

// ---------------------------------------------------------------- utilities
__global__ void zero_ints(int* __restrict__ p, int n) {
    int i = blockIdx.x * blockDim.x + threadIdx.x;
    if (i < n) p[i] = 0;
}

__global__ void count_deg(const int* __restrict__ ei, int E, int* __restrict__ deg) {
    int e = blockIdx.x * blockDim.x + threadIdx.x;
    if (e < E) atomicAdd(&deg[ei[E + e]], 1);   // dst = ei[E + e]
}

// single-block exclusive scan of deg[N] -> offs[N+1]
__global__ __launch_bounds__(1024) void scan_kernel(const int* __restrict__ deg, int N,
                                                    int* __restrict__ offs) {
    __shared__ int sp[1024];
    int t = threadIdx.x;
    int per = (N + 1023) >> 10;
    int base = t * per;
    int sum = 0;
    for (int i = 0; i < per; ++i) {
        int idx = base + i;
        if (idx < N) sum += deg[idx];
    }
    sp[t] = sum;
    __syncthreads();
    for (int off = 1; off < 1024; off <<= 1) {
        int v = (t >= off) ? sp[t - off] : 0;
        __syncthreads();
        sp[t] += v;
        __syncthreads();
    }
    int run = sp[t] - sum;   // exclusive prefix
    for (int i = 0; i < per; ++i) {
        int idx = base + i;
        if (idx < N) { offs[idx] = run; run += deg[idx]; }
    }
    if (t == 1023) offs[N] = sp[1023];
}

// ------------------------------------------------- edge scores + CSR scatter
// 32 edges per block, 8 threads (one per head) per edge.
__global__ __launch_bounds__(256) void score_scatter(
    const int* __restrict__ ei, int E,
    const float* __restrict__ Q, const float* __restrict__ Kp,
    const float* __restrict__ ef, const float* __restrict__ We,
    const int* __restrict__ offs, int* __restrict__ cur,
    float* __restrict__ scb, int* __restrict__ sbuf)
{
    __shared__ float We_s[DEe * Hh];      // 96x8
    __shared__ float ef_s[32][100];       // padded: banks (4*el + i) % 32, conflict-free
    int tid = threadIdx.x;
    for (int i = tid; i < DEe * Hh; i += 256) We_s[i] = We[i];

    int e0 = blockIdx.x * 32;
    // stage 32 edge_feat rows (24 float4 each)
    #pragma unroll
    for (int rep = 0; rep < 3; ++rep) {
        int idx = tid + 256 * rep;        // 0..767
        int el = idx / 24, c4 = idx % 24;
        int e = e0 + el;
        float4 v = make_float4(0.f, 0.f, 0.f, 0.f);
        if (e < E) v = *(const float4*)&ef[(size_t)e * DEe + c4 * 4];
        *(float4*)&ef_s[el][c4 * 4] = v;
    }
    __syncthreads();

    int el = tid >> 3, h = tid & 7;
    int e = e0 + el;
    if (e >= E) return;
    int src = ei[e];
    int dst = ei[E + e];

    const float4* qp = (const float4*)(Q  + (size_t)dst * Dm + h * DHh);
    const float4* kp = (const float4*)(Kp + (size_t)src * Dm + h * DHh);
    float dot = 0.f;
    #pragma unroll
    for (int t = 0; t < 6; ++t) {
        float4 a = qp[t], b = kp[t];
        dot += a.x * b.x + a.y * b.y + a.z * b.z + a.w * b.w;
    }
    float epj = 0.f;
    #pragma unroll 8
    for (int i = 0; i < DEe; ++i) epj += ef_s[el][i] * We_s[i * Hh + h];

    float s = (dot * 0.20412414523193154f + epj) * LOG2E;   // log2 domain

    int lane = tid & 63;
    int pos = 0;
    if (h == 0) pos = offs[dst] + atomicAdd(&cur[dst], 1);
    pos = __shfl(pos, lane & ~7, 64);
    scb[(size_t)pos * 8 + h] = s;
    if (h == 0) sbuf[pos] = src;
}

// ------------------------------------------------- per-node online softmax+PV
// one wave per node; lane owns dims {lane, lane+64, lane+128}
__global__ __launch_bounds__(256) void node_agg(
    const float* __restrict__ V, const float* __restrict__ scb,
    const int* __restrict__ sbuf, const int* __restrict__ offs,
    int N, float* __restrict__ agg)
{
    int node = blockIdx.x * 4 + (threadIdx.x >> 6);
    if (node >= N) return;
    int lane = threadIdx.x & 63;
    int d0 = lane, d1 = lane + 64, d2 = lane + 128;
    int h0 = d0 / DHh, h1 = d1 / DHh, h2 = d2 / DHh;

    float m0 = -1e30f, m1 = -1e30f, m2 = -1e30f;
    float den0 = 0.f, den1 = 0.f, den2 = 0.f;
    float a0 = 0.f, a1 = 0.f, a2 = 0.f;

    int beg = offs[node], end = offs[node + 1];
    for (int idx = beg; idx < end; ++idx) {
        int src = sbuf[idx];
        const float* sp = scb + (size_t)idx * 8;
        float s0 = sp[h0], s1 = sp[h1], s2 = sp[h2];
        const float* vr = V + (size_t)src * Dm;
        float v0 = vr[d0], v1 = vr[d1], v2 = vr[d2];
        float nm, r, p;
        nm = fmaxf(m0, s0); r = exp2f(m0 - nm); p = exp2f(s0 - nm);
        den0 = den0 * r + p; a0 = a0 * r + p * v0; m0 = nm;
        nm = fmaxf(m1, s1); r = exp2f(m1 - nm); p = exp2f(s1 - nm);
        den1 = den1 * r + p; a1 = a1 * r + p * v1; m1 = nm;
        nm = fmaxf(m2, s2); r = exp2f(m2 - nm); p = exp2f(s2 - nm);
        den2 = den2 * r + p; a2 = a2 * r + p * v2; m2 = nm;
    }
    float* og = agg + (size_t)node * Dm;
    og[d0] = a0 / (den0 + 1e-8f);
    og[d1] = a1 / (den1 + 1e-8f);
    og[d2] = a2 / (den2 + 1e-8f);
}

// ------------------------------------------------- fused fp32 GEMM
// C[M, Nout] = A[M, K] @ W[K, Nout]; BM=64, BN=192, BK=64; 256 thr, acc 8x6
__global__ __launch_bounds__(256) void gemm_fused(
    const float* __restrict__ A0, const float* __restrict__ A1, int lda,
    int M, int K,
    const float* __restrict__ W, int ldw,
    const float* __restrict__ bias,
    float* __restrict__ out, int ldo,
    int mode,
    const float* __restrict__ ep0, const float* __restrict__ ep1,
    const float* __restrict__ lns, const float* __restrict__ lnb)
{
    __shared__ float As[64][64];     // 16 KB ([row][k], a-reads 2-addr broadcast = free)
    __shared__ float Ws[64][192];    // 48 KB
    int tid = threadIdx.x;
    int ty = tid >> 5, tx = tid & 31;
    int m0 = blockIdx.x * 64;
    int n0 = blockIdx.y * 192;

    float acc[8][6];
    #pragma unroll
    for (int i = 0; i < 8; ++i)
        #pragma unroll
        for (int j = 0; j < 6; ++j) acc[i][j] = 0.f;

    for (int k0 = 0; k0 < K; k0 += 64) {
        // stage A tile (64 rows x 64 k)
        #pragma unroll
        for (int rep = 0; rep < 4; ++rep) {
            int idx = tid + 256 * rep;            // 0..1023
            int row = idx >> 4, c4 = idx & 15;
            int r = m0 + row; if (r > M - 1) r = M - 1;
            int kg = k0 + c4 * 4;
            const float* base; int stride, kk;
            if (A1 && kg >= 192) { base = A1; stride = 192; kk = kg - 192; }
            else                 { base = A0; stride = lda; kk = kg; }
            float4 v = *(const float4*)&base[(size_t)r * stride + kk];
            *(float4*)&As[row][c4 * 4] = v;
        }
        // stage W tile (64 k x 192 n)
        #pragma unroll
        for (int rep = 0; rep < 12; ++rep) {
            int idx = tid + 256 * rep;            // 0..3071
            int kk = idx / 48, c4 = idx % 48;
            float4 v = *(const float4*)&W[(size_t)(k0 + kk) * ldw + n0 + c4 * 4];
            *(float4*)&Ws[kk][c4 * 4] = v;
        }
        __syncthreads();
        #pragma unroll 4
        for (int kk = 0; kk < 64; ++kk) {
            float a[8], w[6];
            #pragma unroll
            for (int i = 0; i < 8; ++i) a[i] = As[ty * 8 + i][kk];
            #pragma unroll
            for (int j = 0; j < 6; ++j) w[j] = Ws[kk][tx + 32 * j];
            #pragma unroll
            for (int i = 0; i < 8; ++i)
                #pragma unroll
                for (int j = 0; j < 6; ++j) acc[i][j] = fmaf(a[i], w[j], acc[i][j]);
        }
        __syncthreads();
    }

    float bz[6];
    #pragma unroll
    for (int j = 0; j < 6; ++j) bz[j] = bias ? bias[n0 + tx + 32 * j] : 0.f;

    if (mode <= M_SILU) {
        #pragma unroll
        for (int i = 0; i < 8; ++i) {
            int r = m0 + ty * 8 + i;
            if (r < M) {
                #pragma unroll
                for (int j = 0; j < 6; ++j) {
                    float z = acc[i][j] + bz[j];
                    if (mode == M_SILU) z = z / (1.f + expf(-z));
                    out[(size_t)r * ldo + n0 + tx + 32 * j] = z;
                }
            }
        }
        return;
    }

    // LN modes (Nout==192, n0==0). Compute pre-LN value into acc, then row LN.
    float s1v[8], s2v[8];
    #pragma unroll
    for (int i = 0; i < 8; ++i) {
        int r = m0 + ty * 8 + i;
        int rc = r < M ? r : M - 1;
        float s1 = 0.f, s2 = 0.f;
        #pragma unroll
        for (int j = 0; j < 6; ++j) {
            int c = tx + 32 * j;
            float z = acc[i][j] + bz[j];
            float val;
            if (mode == M_GATE_LN) {
                float g  = 1.f / (1.f + expf(-z));
                float ov = ep0[(size_t)rc * 192 + c];
                float xv = ep1[(size_t)rc * 192 + c];
                val = g * ov + (1.f - g) * xv;
            } else {  // M_RES_LN
                val = z + ep0[(size_t)rc * 192 + c];
            }
            acc[i][j] = val;
            s1 += val; s2 += val * val;
        }
        #pragma unroll
        for (int mS = 1; mS < 32; mS <<= 1) {
            s1 += __shfl_xor(s1, mS, 64);
            s2 += __shfl_xor(s2, mS, 64);
        }
        s1v[i] = s1; s2v[i] = s2;
    }
    #pragma unroll
    for (int i = 0; i < 8; ++i) {
        int r = m0 + ty * 8 + i;
        if (r >= M) continue;
        float mean = s1v[i] * (1.f / 192.f);
        float var  = s2v[i] * (1.f / 192.f) - mean * mean;
        float inv  = rsqrtf(var + 1e-5f);
        #pragma unroll
        for (int j = 0; j < 6; ++j) {
            int c = tx + 32 * j;
            out[(size_t)r * 192 + c] = (acc[i][j] - mean) * inv * lns[c] + lnb[c];
        }
    }
}

// ---------------------------------------------------------------- launcher
extern "C" void kernel_launch(void* const* d_in, const int* in_sizes, int n_in,
                              void* d_out, int out_size, void* d_ws, size_t ws_size,
                              hipStream_t stream) {
    const float* x   = (const float*)d_in[0];
    const float* ef  = (const float*)d_in[1];
    const int*   ei  = (const int*)d_in[2];
    const float* Wq  = (const float*)d_in[3];
    const float* Wk  = (const float*)d_in[4];
    const float* Wv  = (const float*)d_in[5];
    const float* We  = (const float*)d_in[6];
    const float* Wo  = (const float*)d_in[7];
    const float* bo  = (const float*)d_in[8];
    const float* Wg  = (const float*)d_in[9];
    const float* bg  = (const float*)d_in[10];
    const float* l1s = (const float*)d_in[11];
    const float* l1b = (const float*)d_in[12];
    const float* Wf1 = (const float*)d_in[13];
    const float* bf1 = (const float*)d_in[14];
    const float* Wf2 = (const float*)d_in[15];
    const float* bf2 = (const float*)d_in[16];
    const float* l2s = (const float*)d_in[17];
    const float* l2b = (const float*)d_in[18];

    int N = in_sizes[0] / Dm;
    int E = in_sizes[1] / DEe;
    float* out = (float*)d_out;

    // workspace carve (256B aligned)
    char* wp = (char*)d_ws;
    auto alloc = [&](size_t bytes) -> void* {
        void* p = wp;
        wp += (bytes + 255) & ~(size_t)255;
        return p;
    };
    size_t NF = (size_t)N * Dm;
    float* Q    = (float*)alloc(NF * 4);
    float* Kb   = (float*)alloc(NF * 4);
    float* Vb   = (float*)alloc(NF * 4);
    float* scb  = (float*)alloc((size_t)E * 8 * 4);
    int*   sbuf = (int*)  alloc((size_t)E * 4);
    int*   deg  = (int*)  alloc((size_t)N * 4);
    int*   cur  = (int*)  alloc((size_t)N * 4);
    int*   offs = (int*)  alloc((size_t)(N + 1) * 4);
    float* ff1  = (float*)alloc((size_t)N * 384 * 4);
    float* agg = Q;    // Q dead after score_scatter
    float* ob  = Kb;   // K dead after score_scatter
    float* yb  = Vb;   // V dead after node_agg

    int gm = (N + 63) / 64;

    zero_ints<<<dim3((N + 255) / 256), 256, 0, stream>>>(deg, N);
    zero_ints<<<dim3((N + 255) / 256), 256, 0, stream>>>(cur, N);

    // Q,K,V projections
    gemm_fused<<<dim3(gm, 1), 256, 0, stream>>>(x, nullptr, Dm, N, Dm, Wq, Dm,
        nullptr, Q, Dm, M_NONE, nullptr, nullptr, nullptr, nullptr);
    gemm_fused<<<dim3(gm, 1), 256, 0, stream>>>(x, nullptr, Dm, N, Dm, Wk, Dm,
        nullptr, Kb, Dm, M_NONE, nullptr, nullptr, nullptr, nullptr);
    gemm_fused<<<dim3(gm, 1), 256, 0, stream>>>(x, nullptr, Dm, N, Dm, Wv, Dm,
        nullptr, Vb, Dm, M_NONE, nullptr, nullptr, nullptr, nullptr);

    // CSR build
    count_deg<<<dim3((E + 255) / 256), 256, 0, stream>>>(ei, E, deg);
    scan_kernel<<<dim3(1), 1024, 0, stream>>>(deg, N, offs);

    // edge scores (log2 domain) scattered into CSR order
    score_scatter<<<dim3((E + 31) / 32), 256, 0, stream>>>(ei, E, Q, Kb, ef, We,
        offs, cur, scb, sbuf);

    // per-node online softmax + weighted V aggregation
    node_agg<<<dim3((N + 3) / 4), 256, 0, stream>>>(Vb, scb, sbuf, offs, N, agg);

    // o = agg @ Wo + bo
    gemm_fused<<<dim3(gm, 1), 256, 0, stream>>>(agg, nullptr, Dm, N, Dm, Wo, Dm,
        bo, ob, Dm, M_BIAS, nullptr, nullptr, nullptr, nullptr);

    // g = sigmoid(concat(o,x) @ Wg + bg); y = LN1(g*o + (1-g)*x)
    gemm_fused<<<dim3(gm, 1), 256, 0, stream>>>(ob, x, Dm, N, 2 * Dm, Wg, Dm,
        bg, yb, Dm, M_GATE_LN, ob, x, l1s, l1b);

    // ff1 = silu(y @ Wf1 + bf1)   [N, 384]
    gemm_fused<<<dim3(gm, 2), 256, 0, stream>>>(yb, nullptr, Dm, N, Dm, Wf1, 384,
        bf1, ff1, 384, M_SILU, nullptr, nullptr, nullptr, nullptr);

    // out = LN2(y + ff1 @ Wf2 + bf2)
    gemm_fused<<<dim3(gm, 1), 256, 0, stream>>>(ff1, nullptr, 384, N, 384, Wf2, Dm,
        bf2, out, Dm, M_RES_LN, yb, nullptr, l2s, l2b);
}

// Round 2
// 356.277 us; speedup vs baseline: 1.7231x; 1.7231x over previous
//
#include <hip/hip_runtime.h>
#include <cstdint>
#include <cstddef>

#define LOG2E 1.4426950408889634f

constexpr int Dm  = 192;
constexpr int DEe = 96;

enum { M_NONE = 0, M_BIAS = 1, M_SILU = 2, M_GATE_LN = 3, M_RES_LN = 4 };

typedef unsigned short u16;
typedef __attribute__((ext_vector_type(8))) short short8v;
typedef __attribute__((ext_vector_type(4))) float f32x4;

__device__ __forceinline__ u16 f2bf(float f) {
    uint32_t u = __builtin_bit_cast(uint32_t, f);
    uint32_t r = (u + 0x7FFF + ((u >> 16) & 1)) >> 16;
    return (u16)r;
}
__device__ __forceinline__ float bf2f(u16 h) {
    uint32_t u = ((uint32_t)h) << 16;
    return __builtin_bit_cast(float, u);
}

// ---------------------------------------------------------------- utilities
__global__ void zero_ints(int* __restrict__ p, int n) {
    int i = blockIdx.x * blockDim.x + threadIdx.x;
    if (i < n) p[i] = 0;
}

__global__ void count_deg(const int* __restrict__ ei, int E, int* __restrict__ deg) {
    int e = blockIdx.x * blockDim.x + threadIdx.x;
    if (e < E) atomicAdd(&deg[ei[E + e]], 1);
}

__global__ __launch_bounds__(1024) void scan_kernel(const int* __restrict__ deg, int N,
                                                    int* __restrict__ offs) {
    __shared__ int sp[1024];
    int t = threadIdx.x;
    int per = (N + 1023) >> 10;
    int base = t * per;
    int sum = 0;
    for (int i = 0; i < per; ++i) {
        int idx = base + i;
        if (idx < N) sum += deg[idx];
    }
    sp[t] = sum;
    __syncthreads();
    for (int off = 1; off < 1024; off <<= 1) {
        int v = (t >= off) ? sp[t - off] : 0;
        __syncthreads();
        sp[t] += v;
        __syncthreads();
    }
    int run = sp[t] - sum;
    for (int i = 0; i < per; ++i) {
        int idx = base + i;
        if (idx < N) { offs[idx] = run; run += deg[idx]; }
    }
    if (t == 1023) offs[N] = sp[1023];
}

// fp32 -> bf16 (vectorized float4 -> ushort4)
__global__ void xconv(const float* __restrict__ x, int n4, u16* __restrict__ xb) {
    int i = blockIdx.x * blockDim.x + threadIdx.x;
    if (i >= n4) return;
    float4 v = ((const float4*)x)[i];
    ushort4 o;
    o.x = f2bf(v.x); o.y = f2bf(v.y); o.z = f2bf(v.z); o.w = f2bf(v.w);
    ((ushort4*)xb)[i] = o;
}

// W [K, Nout] fp32 -> Wt [Nout, K] bf16
__global__ void wconv(const float* __restrict__ W, int K, int Nout, u16* __restrict__ Wt) {
    int idx = blockIdx.x * blockDim.x + threadIdx.x;
    if (idx >= K * Nout) return;
    int n = idx / K, k = idx - n * K;
    Wt[idx] = f2bf(W[(size_t)k * Nout + n]);
}

// ------------------------------------------------- edge-feature projection (stream)
__global__ __launch_bounds__(256) void escore_k(const float* __restrict__ ef,
                                                const float* __restrict__ We, int E,
                                                float* __restrict__ es) {
    __shared__ float We_s[DEe * 8];
    __shared__ float ef_s[32][100];
    int tid = threadIdx.x;
    for (int i = tid; i < DEe * 8; i += 256) We_s[i] = We[i];
    int e0 = blockIdx.x * 32;
    #pragma unroll
    for (int rep = 0; rep < 3; ++rep) {
        int idx = tid + 256 * rep;
        int el = idx / 24, c4 = idx % 24;
        int e = e0 + el;
        float4 v = make_float4(0.f, 0.f, 0.f, 0.f);
        if (e < E) v = *(const float4*)&ef[(size_t)e * DEe + c4 * 4];
        *(float4*)&ef_s[el][c4 * 4] = v;
    }
    __syncthreads();
    int el = tid >> 3, h = tid & 7;
    int e = e0 + el;
    if (e >= E) return;
    float epj = 0.f;
    #pragma unroll 8
    for (int i = 0; i < DEe; ++i) epj += ef_s[el][i] * We_s[i * 8 + h];
    es[(size_t)e * 8 + h] = epj;
}

// ------------------------------------------------- QK dot + CSR scatter (gather)
__global__ __launch_bounds__(256) void score_scatter2(
    const int* __restrict__ ei, int E,
    const u16* __restrict__ qkv,          // [N][576] bf16: Q|K|V
    const float* __restrict__ es,
    const int* __restrict__ offs, int* __restrict__ cur,
    float* __restrict__ scb, int* __restrict__ sbuf)
{
    int tid = threadIdx.x;
    int el = tid >> 3, h = tid & 7;
    int e = blockIdx.x * 32 + el;
    if (e >= E) return;
    int src = ei[e];
    int dst = ei[E + e];

    const short8v* qp = (const short8v*)(qkv + (size_t)dst * 576 + h * 24);
    const short8v* kp = (const short8v*)(qkv + (size_t)src * 576 + 192 + h * 24);
    float dot = 0.f;
    #pragma unroll
    for (int t = 0; t < 3; ++t) {
        short8v qa = qp[t], kb = kp[t];
        #pragma unroll
        for (int j = 0; j < 8; ++j) dot += bf2f((u16)qa[j]) * bf2f((u16)kb[j]);
    }
    float s = (dot * 0.20412414523193154f + es[(size_t)e * 8 + h]) * LOG2E;

    int lane = tid & 63;
    int pos = 0;
    if (h == 0) pos = offs[dst] + atomicAdd(&cur[dst], 1);
    pos = __shfl(pos, lane & 56, 64);
    scb[(size_t)pos * 8 + h] = s;
    if (h == 0) sbuf[pos] = src;
}

// ------------------------------------------------- per-node online softmax + PV
__global__ __launch_bounds__(256) void node_agg(
    const u16* __restrict__ qkv, const float* __restrict__ scb,
    const int* __restrict__ sbuf, const int* __restrict__ offs,
    int N, u16* __restrict__ aggb)
{
    int node = blockIdx.x * 4 + (threadIdx.x >> 6);
    if (node >= N) return;
    int lane = threadIdx.x & 63;
    int d0 = lane, d1 = lane + 64, d2 = lane + 128;
    int h0 = d0 / 24, h1 = d1 / 24, h2 = d2 / 24;

    float m0 = -1e30f, m1 = -1e30f, m2 = -1e30f;
    float den0 = 0.f, den1 = 0.f, den2 = 0.f;
    float a0 = 0.f, a1 = 0.f, a2 = 0.f;

    int beg = offs[node], end = offs[node + 1];
    for (int idx = beg; idx < end; ++idx) {
        int src = sbuf[idx];
        const float* sp = scb + (size_t)idx * 8;
        float s0 = sp[h0], s1 = sp[h1], s2 = sp[h2];
        const u16* vr = qkv + (size_t)src * 576 + 384;
        float v0 = bf2f(vr[d0]), v1 = bf2f(vr[d1]), v2 = bf2f(vr[d2]);
        float nm, r, p;
        nm = fmaxf(m0, s0); r = exp2f(m0 - nm); p = exp2f(s0 - nm);
        den0 = den0 * r + p; a0 = a0 * r + p * v0; m0 = nm;
        nm = fmaxf(m1, s1); r = exp2f(m1 - nm); p = exp2f(s1 - nm);
        den1 = den1 * r + p; a1 = a1 * r + p * v1; m1 = nm;
        nm = fmaxf(m2, s2); r = exp2f(m2 - nm); p = exp2f(s2 - nm);
        den2 = den2 * r + p; a2 = a2 * r + p * v2; m2 = nm;
    }
    u16* og = aggb + (size_t)node * Dm;
    og[d0] = f2bf(a0 / (den0 + 1e-8f));
    og[d1] = f2bf(a1 / (den1 + 1e-8f));
    og[d2] = f2bf(a2 / (den2 + 1e-8f));
}

// ------------------------------------------------- bf16 MFMA GEMM, fused epilogues
// C[M,Nout] = A[M,K] @ W[K,Nout]; BM=64, BN=192, BK=32; 256 thr = 4 waves,
// wave w owns cols [w*48, w*48+48). Wt is [Nout][K] bf16 (pre-transposed).
__global__ __launch_bounds__(256) void gemm_mfma(
    const u16* __restrict__ A0, const u16* __restrict__ A1, int lda0,
    int M, int K,
    const u16* __restrict__ Wt,
    const float* __restrict__ bias,
    u16* __restrict__ outB, float* __restrict__ outF, int ldo,
    int mode,
    const u16* __restrict__ ep0, const u16* __restrict__ ep1,
    const float* __restrict__ lns, const float* __restrict__ lnb)
{
    __shared__ __align__(16) short As[64 * 40];    // row stride 80 B
    __shared__ __align__(16) short Bs[192 * 40];
    __shared__ float red[2][4][64];

    int tid = threadIdx.x;
    int m0 = blockIdx.x * 64;
    int n0 = blockIdx.y * 192;
    int w = tid >> 6, lane = tid & 63;
    int c16 = lane & 15, hi2 = lane >> 4;

    int rs = tid >> 2, qs = tid & 3;               // staging row / 16B quarter
    int arow = m0 + rs; if (arow > M - 1) arow = M - 1;

    f32x4 acc[4][3];
    #pragma unroll
    for (int mr = 0; mr < 4; ++mr)
        #pragma unroll
        for (int nr = 0; nr < 3; ++nr) acc[mr][nr] = (f32x4)(0.f);

    int nk = K >> 5;
    short8v ra, rb0, rb1, rb2;
    auto loadA = [&](int ks) {
        int kg = ks * 32 + qs * 8;
        const u16* base; int ld, kk;
        if (A1 && kg >= 192) { base = A1; ld = 192; kk = kg - 192; }
        else                 { base = A0; ld = lda0; kk = kg; }
        ra = *(const short8v*)(base + (size_t)arow * ld + kk);
    };
    auto loadB = [&](int ks) {
        int kg = ks * 32 + qs * 8;
        const u16* b = Wt + (size_t)(n0 + rs) * K + kg;
        rb0 = *(const short8v*)b;
        rb1 = *(const short8v*)(b + (size_t)64 * K);
        rb2 = *(const short8v*)(b + (size_t)128 * K);
    };
    loadA(0); loadB(0);

    for (int ks = 0; ks < nk; ++ks) {
        *(short8v*)&As[rs * 40 + qs * 8] = ra;
        *(short8v*)&Bs[rs * 40 + qs * 8] = rb0;
        *(short8v*)&Bs[(rs + 64) * 40 + qs * 8] = rb1;
        *(short8v*)&Bs[(rs + 128) * 40 + qs * 8] = rb2;
        __syncthreads();
        if (ks + 1 < nk) { loadA(ks + 1); loadB(ks + 1); }
        short8v af[4], bf[3];
        #pragma unroll
        for (int mr = 0; mr < 4; ++mr)
            af[mr] = *(const short8v*)&As[(mr * 16 + c16) * 40 + hi2 * 8];
        #pragma unroll
        for (int nr = 0; nr < 3; ++nr)
            bf[nr] = *(const short8v*)&Bs[(w * 48 + nr * 16 + c16) * 40 + hi2 * 8];
        #pragma unroll
        for (int mr = 0; mr < 4; ++mr)
            #pragma unroll
            for (int nr = 0; nr < 3; ++nr)
                acc[mr][nr] = __builtin_amdgcn_mfma_f32_16x16x32_bf16(
                    af[mr], bf[nr], acc[mr][nr], 0, 0, 0);
        __syncthreads();
    }

    float bz[3];
    #pragma unroll
    for (int nr = 0; nr < 3; ++nr)
        bz[nr] = bias ? bias[n0 + w * 48 + nr * 16 + c16] : 0.f;

    if (mode <= M_SILU) {
        #pragma unroll
        for (int mr = 0; mr < 4; ++mr)
            #pragma unroll
            for (int reg = 0; reg < 4; ++reg) {
                int r = m0 + mr * 16 + hi2 * 4 + reg;
                if (r >= M) continue;
                #pragma unroll
                for (int nr = 0; nr < 3; ++nr) {
                    float z = acc[mr][nr][reg] + bz[nr];
                    if (mode == M_SILU) z = z / (1.f + expf(-z));
                    int col = n0 + w * 48 + nr * 16 + c16;
                    outB[(size_t)r * ldo + col] = f2bf(z);
                }
            }
        return;
    }

    // LN modes: Nout = 192, n0 = 0, ldo = 192
    float s1p[4][4], s2p[4][4];
    #pragma unroll
    for (int mr = 0; mr < 4; ++mr)
        #pragma unroll
        for (int reg = 0; reg < 4; ++reg) {
            int r = m0 + mr * 16 + hi2 * 4 + reg;
            int rc = r < M ? r : M - 1;
            float s1 = 0.f, s2 = 0.f;
            #pragma unroll
            for (int nr = 0; nr < 3; ++nr) {
                int col = w * 48 + nr * 16 + c16;
                float z = acc[mr][nr][reg] + bz[nr];
                float val;
                if (mode == M_GATE_LN) {
                    float g  = 1.f / (1.f + expf(-z));
                    float ov = bf2f(ep0[(size_t)rc * 192 + col]);
                    float xv = bf2f(ep1[(size_t)rc * 192 + col]);
                    val = g * ov + (1.f - g) * xv;
                } else {
                    val = z + bf2f(ep0[(size_t)rc * 192 + col]);
                }
                acc[mr][nr][reg] = val;
                s1 += val; s2 += val * val;
            }
            #pragma unroll
            for (int mS = 1; mS < 16; mS <<= 1) {
                s1 += __shfl_xor(s1, mS, 64);
                s2 += __shfl_xor(s2, mS, 64);
            }
            s1p[mr][reg] = s1; s2p[mr][reg] = s2;
        }
    if (c16 == 0) {
        #pragma unroll
        for (int mr = 0; mr < 4; ++mr)
            #pragma unroll
            for (int reg = 0; reg < 4; ++reg) {
                int rowIdx = mr * 16 + hi2 * 4 + reg;
                red[0][w][rowIdx] = s1p[mr][reg];
                red[1][w][rowIdx] = s2p[mr][reg];
            }
    }
    __syncthreads();
    #pragma unroll
    for (int mr = 0; mr < 4; ++mr)
        #pragma unroll
        for (int reg = 0; reg < 4; ++reg) {
            int rowIdx = mr * 16 + hi2 * 4 + reg;
            int r = m0 + rowIdx;
            if (r >= M) continue;
            float S1 = red[0][0][rowIdx] + red[0][1][rowIdx] + red[0][2][rowIdx] + red[0][3][rowIdx];
            float S2 = red[1][0][rowIdx] + red[1][1][rowIdx] + red[1][2][rowIdx] + red[1][3][rowIdx];
            float mean = S1 * (1.f / 192.f);
            float var  = S2 * (1.f / 192.f) - mean * mean;
            float inv  = rsqrtf(var + 1e-5f);
            #pragma unroll
            for (int nr = 0; nr < 3; ++nr) {
                int col = w * 48 + nr * 16 + c16;
                float res = (acc[mr][nr][reg] - mean) * inv * lns[col] + lnb[col];
                if (mode == M_RES_LN) outF[(size_t)r * 192 + col] = res;
                else                  outB[(size_t)r * 192 + col] = f2bf(res);
            }
        }
}

// ---------------------------------------------------------------- launcher
extern "C" void kernel_launch(void* const* d_in, const int* in_sizes, int n_in,
                              void* d_out, int out_size, void* d_ws, size_t ws_size,
                              hipStream_t stream) {
    const float* x   = (const float*)d_in[0];
    const float* ef  = (const float*)d_in[1];
    const int*   ei  = (const int*)d_in[2];
    const float* Wq  = (const float*)d_in[3];
    const float* Wk  = (const float*)d_in[4];
    const float* Wv  = (const float*)d_in[5];
    const float* We  = (const float*)d_in[6];
    const float* Wo  = (const float*)d_in[7];
    const float* bo  = (const float*)d_in[8];
    const float* Wg  = (const float*)d_in[9];
    const float* bg  = (const float*)d_in[10];
    const float* l1s = (const float*)d_in[11];
    const float* l1b = (const float*)d_in[12];
    const float* Wf1 = (const float*)d_in[13];
    const float* bf1 = (const float*)d_in[14];
    const float* Wf2 = (const float*)d_in[15];
    const float* bf2 = (const float*)d_in[16];
    const float* l2s = (const float*)d_in[17];
    const float* l2b = (const float*)d_in[18];

    int N = in_sizes[0] / Dm;
    int E = in_sizes[1] / DEe;
    float* out = (float*)d_out;

    char* wp = (char*)d_ws;
    auto alloc = [&](size_t bytes) -> void* {
        void* p = wp;
        wp += (bytes + 255) & ~(size_t)255;
        return p;
    };
    size_t NF = (size_t)N * Dm;
    u16*   xb    = (u16*)alloc(NF * 2);
    u16*   qkvb  = (u16*)alloc((size_t)N * 576 * 2);
    u16*   aggb  = (u16*)alloc(NF * 2);
    float* es    = (float*)alloc((size_t)E * 8 * 4);
    float* scb   = (float*)alloc((size_t)E * 8 * 4);
    int*   sbuf  = (int*)  alloc((size_t)E * 4);
    int*   deg   = (int*)  alloc((size_t)N * 4);
    int*   cur   = (int*)  alloc((size_t)N * 4);
    int*   offs  = (int*)  alloc((size_t)(N + 1) * 4);
    u16*   Wqkvt = (u16*)alloc((size_t)576 * 192 * 2);
    u16*   Wot   = (u16*)alloc((size_t)192 * 192 * 2);
    u16*   Wgt   = (u16*)alloc((size_t)192 * 384 * 2);
    u16*   Wf1t  = (u16*)alloc((size_t)384 * 192 * 2);
    u16*   Wf2t  = (u16*)alloc((size_t)192 * 384 * 2);
    // aliases (lifetimes disjoint)
    u16* ob   = qkvb;                 // after node_agg, qkv dead
    u16* yb   = qkvb + 4800000;       // N*192
    u16* ff1b = (u16*)es;             // es+scb dead after node_agg

    int gm = (N + 63) / 64;

    zero_ints<<<dim3((N + 255) / 256), 256, 0, stream>>>(deg, N);
    zero_ints<<<dim3((N + 255) / 256), 256, 0, stream>>>(cur, N);
    xconv<<<dim3((N * Dm / 4 + 255) / 256), 256, 0, stream>>>(x, N * Dm / 4, xb);

    wconv<<<dim3((192 * 192 + 255) / 256), 256, 0, stream>>>(Wq, 192, 192, Wqkvt);
    wconv<<<dim3((192 * 192 + 255) / 256), 256, 0, stream>>>(Wk, 192, 192, Wqkvt + 192 * 192);
    wconv<<<dim3((192 * 192 + 255) / 256), 256, 0, stream>>>(Wv, 192, 192, Wqkvt + 384 * 192);
    wconv<<<dim3((192 * 192 + 255) / 256), 256, 0, stream>>>(Wo, 192, 192, Wot);
    wconv<<<dim3((384 * 192 + 255) / 256), 256, 0, stream>>>(Wg, 384, 192, Wgt);
    wconv<<<dim3((192 * 384 + 255) / 256), 256, 0, stream>>>(Wf1, 192, 384, Wf1t);
    wconv<<<dim3((384 * 192 + 255) / 256), 256, 0, stream>>>(Wf2, 384, 192, Wf2t);

    count_deg<<<dim3((E + 255) / 256), 256, 0, stream>>>(ei, E, deg);
    scan_kernel<<<dim3(1), 1024, 0, stream>>>(deg, N, offs);

    // QKV fused: [N,192] @ [192,576] -> qkvb bf16
    gemm_mfma<<<dim3(gm, 3), 256, 0, stream>>>(xb, nullptr, Dm, N, 192, Wqkvt,
        nullptr, qkvb, nullptr, 576, M_NONE, nullptr, nullptr, nullptr, nullptr);

    escore_k<<<dim3((E + 31) / 32), 256, 0, stream>>>(ef, We, E, es);
    score_scatter2<<<dim3((E + 31) / 32), 256, 0, stream>>>(ei, E, qkvb, es,
        offs, cur, scb, sbuf);
    node_agg<<<dim3((N + 3) / 4), 256, 0, stream>>>(qkvb, scb, sbuf, offs, N, aggb);

    // o = agg @ Wo + bo  (bf16)
    gemm_mfma<<<dim3(gm, 1), 256, 0, stream>>>(aggb, nullptr, Dm, N, 192, Wot,
        bo, ob, nullptr, Dm, M_BIAS, nullptr, nullptr, nullptr, nullptr);

    // y = LN1(sigmoid(concat(o,x)@Wg+bg) * o + (1-g)*x)
    gemm_mfma<<<dim3(gm, 1), 256, 0, stream>>>(ob, xb, Dm, N, 384, Wgt,
        bg, yb, nullptr, Dm, M_GATE_LN, ob, xb, l1s, l1b);

    // ff1 = silu(y @ Wf1 + bf1)
    gemm_mfma<<<dim3(gm, 2), 256, 0, stream>>>(yb, nullptr, Dm, N, 192, Wf1t,
        bf1, ff1b, nullptr, 384, M_SILU, nullptr, nullptr, nullptr, nullptr);

    // out = LN2(y + ff1 @ Wf2 + bf2)  (fp32)
    gemm_mfma<<<dim3(gm, 1), 256, 0, stream>>>(ff1b, nullptr, 384, N, 384, Wf2t,
        bf2, nullptr, out, Dm, M_RES_LN, yb, nullptr, l2s, l2b);
}

// Round 3
// 307.808 us; speedup vs baseline: 1.9944x; 1.1575x over previous
//
#include <hip/hip_runtime.h>
#include <cstdint>
#include <cstddef>

#define LOG2E 1.4426950408889634f

constexpr int Dm  = 192;
constexpr int DEe = 96;

enum { M_NONE = 0, M_BIAS = 1, M_SILU = 2, M_GATE_LN = 3, M_RES_LN = 4 };

typedef unsigned short u16;
typedef __attribute__((ext_vector_type(8))) short short8v;
typedef __attribute__((ext_vector_type(4))) float f32x4;

__device__ __forceinline__ u16 f2bf(float f) {
    uint32_t u = __builtin_bit_cast(uint32_t, f);
    uint32_t r = (u + 0x7FFF + ((u >> 16) & 1)) >> 16;
    return (u16)r;
}
__device__ __forceinline__ float bf2f(u16 h) {
    uint32_t u = ((uint32_t)h) << 16;
    return __builtin_bit_cast(float, u);
}

// ---------------------------------------------------------------- utilities
__global__ void zero_ints(int* __restrict__ p, int n) {
    int i = blockIdx.x * blockDim.x + threadIdx.x;
    if (i < n) p[i] = 0;
}

__global__ void count_deg(const int* __restrict__ ei, int E, int* __restrict__ deg) {
    int e = blockIdx.x * blockDim.x + threadIdx.x;
    if (e < E) atomicAdd(&deg[ei[E + e]], 1);
}

__global__ __launch_bounds__(1024) void scan_kernel(const int* __restrict__ deg, int N,
                                                    int* __restrict__ offs) {
    __shared__ int sp[1024];
    int t = threadIdx.x;
    int per = (N + 1023) >> 10;
    int base = t * per;
    int sum = 0;
    for (int i = 0; i < per; ++i) {
        int idx = base + i;
        if (idx < N) sum += deg[idx];
    }
    sp[t] = sum;
    __syncthreads();
    for (int off = 1; off < 1024; off <<= 1) {
        int v = (t >= off) ? sp[t - off] : 0;
        __syncthreads();
        sp[t] += v;
        __syncthreads();
    }
    int run = sp[t] - sum;
    for (int i = 0; i < per; ++i) {
        int idx = base + i;
        if (idx < N) { offs[idx] = run; run += deg[idx]; }
    }
    if (t == 1023) offs[N] = sp[1023];
}

// fp32 -> bf16 (vectorized float4 -> ushort4)
__global__ void xconv(const float* __restrict__ x, int n4, u16* __restrict__ xb) {
    int i = blockIdx.x * blockDim.x + threadIdx.x;
    if (i >= n4) return;
    float4 v = ((const float4*)x)[i];
    ushort4 o;
    o.x = f2bf(v.x); o.y = f2bf(v.y); o.z = f2bf(v.z); o.w = f2bf(v.w);
    ((ushort4*)xb)[i] = o;
}

// all weight transposes+conversions in one launch. Wt layouts: [Nout][K] bf16.
__global__ void prep_w(const float* __restrict__ Wq, const float* __restrict__ Wk,
                       const float* __restrict__ Wv, const float* __restrict__ Wo,
                       const float* __restrict__ Wg, const float* __restrict__ Wf1,
                       const float* __restrict__ Wf2,
                       u16* __restrict__ Wqkvt, u16* __restrict__ Wot,
                       u16* __restrict__ Wgt, u16* __restrict__ Wf1t,
                       u16* __restrict__ Wf2t) {
    int idx = blockIdx.x * blockDim.x + threadIdx.x;
    if (idx < 110592) {                    // QKV: [576][192]
        int n = idx / 192, k = idx % 192;
        const float* W = n < 192 ? Wq : (n < 384 ? Wk : Wv);
        Wqkvt[idx] = f2bf(W[(size_t)k * 192 + (n % 192)]);
    } else if (idx < 147456) {             // Wo: [192][192]
        int i = idx - 110592;
        int n = i / 192, k = i % 192;
        Wot[i] = f2bf(Wo[(size_t)k * 192 + n]);
    } else if (idx < 221184) {             // Wg: [192][384]
        int i = idx - 147456;
        int n = i / 384, k = i % 384;
        Wgt[i] = f2bf(Wg[(size_t)k * 192 + n]);
    } else if (idx < 294912) {             // Wf1: [384][192]
        int i = idx - 221184;
        int n = i / 192, k = i % 192;
        Wf1t[i] = f2bf(Wf1[(size_t)k * 384 + n]);
    } else if (idx < 368640) {             // Wf2: [192][384]
        int i = idx - 294912;
        int n = i / 384, k = i % 384;
        Wf2t[i] = f2bf(Wf2[(size_t)k * 192 + n]);
    }
}

// ---------------------------------------- edge prep: ef@We + CSR scatter
// 32 edges/block, 8 threads (one per head) per edge. Writes per-edge bias
// (pre-scaled by LOG2E) into CSR position, and src node id.
__global__ __launch_bounds__(256) void edge_prep(
    const int* __restrict__ ei, int E,
    const float* __restrict__ ef, const float* __restrict__ We,
    const int* __restrict__ offs, int* __restrict__ cur,
    float* __restrict__ scb, int* __restrict__ sbuf)
{
    __shared__ float We_s[DEe * 8];
    __shared__ float ef_s[32][100];
    int tid = threadIdx.x;
    for (int i = tid; i < DEe * 8; i += 256) We_s[i] = We[i];
    int e0 = blockIdx.x * 32;
    #pragma unroll
    for (int rep = 0; rep < 3; ++rep) {
        int idx = tid + 256 * rep;
        int el = idx / 24, c4 = idx % 24;
        int e = e0 + el;
        float4 v = make_float4(0.f, 0.f, 0.f, 0.f);
        if (e < E) v = *(const float4*)&ef[(size_t)e * DEe + c4 * 4];
        *(float4*)&ef_s[el][c4 * 4] = v;
    }
    __syncthreads();
    int el = tid >> 3, h = tid & 7;
    int e = e0 + el;
    if (e >= E) return;
    float epj = 0.f;
    #pragma unroll 8
    for (int i = 0; i < DEe; ++i) epj += ef_s[el][i] * We_s[i * 8 + h];

    int lane = tid & 63;
    int pos = 0;
    if (h == 0) {
        int dst = ei[E + e];
        pos = offs[dst] + atomicAdd(&cur[dst], 1);
    }
    pos = __shfl(pos, lane & 56, 64);
    scb[(size_t)pos * 8 + h] = epj * LOG2E;
    if (h == 0) sbuf[pos] = ei[e];   // src
}

// ---------------------------------------- fused score + softmax + PV per node
// one wave per node; lane l: head h = l>>3, owns dims h*24 + (l&7)*3 .. +3
// (byte offset 6*l within a 384B row). No max-tracking (scores bounded).
__global__ __launch_bounds__(256) void agg_fused(
    const u16* __restrict__ qkv, const float* __restrict__ scb,
    const int* __restrict__ sbuf, const int* __restrict__ offs,
    int N, u16* __restrict__ aggb)
{
    int node = blockIdx.x * 4 + (threadIdx.x >> 6);
    if (node >= N) return;
    int lane = threadIdx.x & 63;
    int h = lane >> 3;
    int di = (3 * lane) >> 1;          // dword index of first byte 6*lane
    int odd = lane & 1;

    // Q row (once per node)
    const uint32_t* qrow = (const uint32_t*)(qkv + (size_t)node * 576);
    uint32_t qd0 = qrow[di], qd1 = qrow[di + 1];
    float q0, q1, q2;
    if (!odd) { q0 = bf2f(qd0 & 0xffff); q1 = bf2f(qd0 >> 16); q2 = bf2f(qd1 & 0xffff); }
    else      { q0 = bf2f(qd0 >> 16);    q1 = bf2f(qd1 & 0xffff); q2 = bf2f(qd1 >> 16); }

    float den = 0.f, a0 = 0.f, a1 = 0.f, a2 = 0.f;
    int beg = offs[node], end = offs[node + 1];

    int src_n = 0; uint32_t kd0_n = 0, kd1_n = 0, vd0_n = 0, vd1_n = 0; float ep_n = 0.f;
    if (beg < end) {
        src_n = sbuf[beg];
        const uint32_t* kr = (const uint32_t*)(qkv + (size_t)src_n * 576 + 192);
        kd0_n = kr[di]; kd1_n = kr[di + 1];
        kd0_n = kd0_n; // keep
        const uint32_t* vr = (const uint32_t*)(qkv + (size_t)src_n * 576 + 384);
        vd0_n = vr[di]; vd1_n = vr[di + 1];
        ep_n = scb[(size_t)beg * 8 + h];
    }

    for (int idx = beg; idx < end; ++idx) {
        uint32_t kd0 = kd0_n, kd1 = kd1_n, vd0 = vd0_n, vd1 = vd1_n;
        float ep = ep_n;
        if (idx + 1 < end) {                       // prefetch next edge
            int src = sbuf[idx + 1];
            const uint32_t* kr = (const uint32_t*)(qkv + (size_t)src * 576 + 192);
            kd0_n = kr[di]; kd1_n = kr[di + 1];
            const uint32_t* vr = (const uint32_t*)(qkv + (size_t)src * 576 + 384);
            vd0_n = vr[di]; vd1_n = vr[di + 1];
            ep_n = scb[(size_t)(idx + 1) * 8 + h];
        }
        float k0, k1, k2, v0, v1, v2;
        if (!odd) {
            k0 = bf2f(kd0 & 0xffff); k1 = bf2f(kd0 >> 16); k2 = bf2f(kd1 & 0xffff);
            v0 = bf2f(vd0 & 0xffff); v1 = bf2f(vd0 >> 16); v2 = bf2f(vd1 & 0xffff);
        } else {
            k0 = bf2f(kd0 >> 16); k1 = bf2f(kd1 & 0xffff); k2 = bf2f(kd1 >> 16);
            v0 = bf2f(vd0 >> 16); v1 = bf2f(vd1 & 0xffff); v2 = bf2f(vd1 >> 16);
        }
        float pd = q0 * k0 + q1 * k1 + q2 * k2;
        pd += __shfl_xor(pd, 1, 64);
        pd += __shfl_xor(pd, 2, 64);
        pd += __shfl_xor(pd, 4, 64);
        // s*log2e = pd * (scale*log2e) + ep  (ep pre-scaled)
        float p = exp2f(pd * 0.2944885836f + ep);
        den += p;
        a0 += p * v0; a1 += p * v1; a2 += p * v2;
    }
    float rden = 1.f / (den + 1e-8f);
    u16* og = aggb + (size_t)node * Dm;
    int b0 = 3 * lane;
    og[b0]     = f2bf(a0 * rden);
    og[b0 + 1] = f2bf(a1 * rden);
    og[b0 + 2] = f2bf(a2 * rden);
}

// ------------------------------------------------- bf16 MFMA GEMM, fused epilogues
// C[M,Nout] = A[M,K] @ W[K,Nout]; BM=64, BN=192, BK=64; 256 thr = 4 waves,
// wave w owns cols [w*48, w*48+48). Wt is [Nout][K] bf16 (pre-transposed).
__global__ __launch_bounds__(256) void gemm_mfma(
    const u16* __restrict__ A0, const u16* __restrict__ A1, int lda0,
    int M, int K,
    const u16* __restrict__ Wt,
    const float* __restrict__ bias,
    u16* __restrict__ outB, float* __restrict__ outF, int ldo,
    int mode,
    const u16* __restrict__ ep0, const u16* __restrict__ ep1,
    const float* __restrict__ lns, const float* __restrict__ lnb)
{
    __shared__ __align__(16) short As[64 * 72];    // row stride 144 B
    __shared__ __align__(16) short Bs[192 * 72];
    __shared__ float red[2][4][64];

    int tid = threadIdx.x;
    int m0 = blockIdx.x * 64;
    int n0 = blockIdx.y * 192;
    int w = tid >> 6, lane = tid & 63;
    int c16 = lane & 15, hi2 = lane >> 4;

    f32x4 acc[4][3];
    #pragma unroll
    for (int mr = 0; mr < 4; ++mr)
        #pragma unroll
        for (int nr = 0; nr < 3; ++nr) acc[mr][nr] = (f32x4)(0.f);

    int nk = K >> 6;                              // BK=64
    short8v ra[2], rb[6];
    auto loadA = [&](int ks) {
        #pragma unroll
        for (int rep = 0; rep < 2; ++rep) {
            int c = tid + 256 * rep;
            int row = c >> 3, kc = c & 7;
            int r = m0 + row; if (r > M - 1) r = M - 1;
            int kg = ks * 64 + kc * 8;
            const u16* base; int ld, kk;
            if (A1 && kg >= 192) { base = A1; ld = 192; kk = kg - 192; }
            else                 { base = A0; ld = lda0; kk = kg; }
            ra[rep] = *(const short8v*)(base + (size_t)r * ld + kk);
        }
    };
    auto loadB = [&](int ks) {
        #pragma unroll
        for (int rep = 0; rep < 6; ++rep) {
            int c = tid + 256 * rep;
            int row = c >> 3, kc = c & 7;
            rb[rep] = *(const short8v*)(Wt + (size_t)(n0 + row) * K + ks * 64 + kc * 8);
        }
    };
    loadA(0); loadB(0);

    for (int ks = 0;;) {
        #pragma unroll
        for (int rep = 0; rep < 2; ++rep) {
            int c = tid + 256 * rep;
            *(short8v*)&As[(c >> 3) * 72 + (c & 7) * 8] = ra[rep];
        }
        #pragma unroll
        for (int rep = 0; rep < 6; ++rep) {
            int c = tid + 256 * rep;
            *(short8v*)&Bs[(c >> 3) * 72 + (c & 7) * 8] = rb[rep];
        }
        __syncthreads();
        ++ks;
        if (ks < nk) { loadA(ks); loadB(ks); }
        #pragma unroll
        for (int kf = 0; kf < 2; ++kf) {
            short8v af[4], bfr[3];
            #pragma unroll
            for (int mr = 0; mr < 4; ++mr)
                af[mr] = *(const short8v*)&As[(mr * 16 + c16) * 72 + kf * 32 + hi2 * 8];
            #pragma unroll
            for (int nr = 0; nr < 3; ++nr)
                bfr[nr] = *(const short8v*)&Bs[(w * 48 + nr * 16 + c16) * 72 + kf * 32 + hi2 * 8];
            #pragma unroll
            for (int mr = 0; mr < 4; ++mr)
                #pragma unroll
                for (int nr = 0; nr < 3; ++nr)
                    acc[mr][nr] = __builtin_amdgcn_mfma_f32_16x16x32_bf16(
                        af[mr], bfr[nr], acc[mr][nr], 0, 0, 0);
        }
        if (ks >= nk) break;
        __syncthreads();
    }

    float bz[3];
    #pragma unroll
    for (int nr = 0; nr < 3; ++nr)
        bz[nr] = bias ? bias[n0 + w * 48 + nr * 16 + c16] : 0.f;

    if (mode <= M_SILU) {
        #pragma unroll
        for (int mr = 0; mr < 4; ++mr)
            #pragma unroll
            for (int reg = 0; reg < 4; ++reg) {
                int r = m0 + mr * 16 + hi2 * 4 + reg;
                if (r >= M) continue;
                #pragma unroll
                for (int nr = 0; nr < 3; ++nr) {
                    float z = acc[mr][nr][reg] + bz[nr];
                    if (mode == M_SILU) z = z / (1.f + expf(-z));
                    int col = n0 + w * 48 + nr * 16 + c16;
                    outB[(size_t)r * ldo + col] = f2bf(z);
                }
            }
        return;
    }

    // LN modes: Nout = 192, n0 = 0, ldo = 192
    float s1p[4][4], s2p[4][4];
    #pragma unroll
    for (int mr = 0; mr < 4; ++mr)
        #pragma unroll
        for (int reg = 0; reg < 4; ++reg) {
            int r = m0 + mr * 16 + hi2 * 4 + reg;
            int rc = r < M ? r : M - 1;
            float s1 = 0.f, s2 = 0.f;
            #pragma unroll
            for (int nr = 0; nr < 3; ++nr) {
                int col = w * 48 + nr * 16 + c16;
                float z = acc[mr][nr][reg] + bz[nr];
                float val;
                if (mode == M_GATE_LN) {
                    float g  = 1.f / (1.f + expf(-z));
                    float ov = bf2f(ep0[(size_t)rc * 192 + col]);
                    float xv = bf2f(ep1[(size_t)rc * 192 + col]);
                    val = g * ov + (1.f - g) * xv;
                } else {
                    val = z + bf2f(ep0[(size_t)rc * 192 + col]);
                }
                acc[mr][nr][reg] = val;
                s1 += val; s2 += val * val;
            }
            #pragma unroll
            for (int mS = 1; mS < 16; mS <<= 1) {
                s1 += __shfl_xor(s1, mS, 64);
                s2 += __shfl_xor(s2, mS, 64);
            }
            s1p[mr][reg] = s1; s2p[mr][reg] = s2;
        }
    if (c16 == 0) {
        #pragma unroll
        for (int mr = 0; mr < 4; ++mr)
            #pragma unroll
            for (int reg = 0; reg < 4; ++reg) {
                int rowIdx = mr * 16 + hi2 * 4 + reg;
                red[0][w][rowIdx] = s1p[mr][reg];
                red[1][w][rowIdx] = s2p[mr][reg];
            }
    }
    __syncthreads();
    #pragma unroll
    for (int mr = 0; mr < 4; ++mr)
        #pragma unroll
        for (int reg = 0; reg < 4; ++reg) {
            int rowIdx = mr * 16 + hi2 * 4 + reg;
            int r = m0 + rowIdx;
            if (r >= M) continue;
            float S1 = red[0][0][rowIdx] + red[0][1][rowIdx] + red[0][2][rowIdx] + red[0][3][rowIdx];
            float S2 = red[1][0][rowIdx] + red[1][1][rowIdx] + red[1][2][rowIdx] + red[1][3][rowIdx];
            float mean = S1 * (1.f / 192.f);
            float var  = S2 * (1.f / 192.f) - mean * mean;
            float inv  = rsqrtf(var + 1e-5f);
            #pragma unroll
            for (int nr = 0; nr < 3; ++nr) {
                int col = w * 48 + nr * 16 + c16;
                float res = (acc[mr][nr][reg] - mean) * inv * lns[col] + lnb[col];
                if (mode == M_RES_LN) outF[(size_t)r * 192 + col] = res;
                else                  outB[(size_t)r * 192 + col] = f2bf(res);
            }
        }
}

// ---------------------------------------------------------------- launcher
extern "C" void kernel_launch(void* const* d_in, const int* in_sizes, int n_in,
                              void* d_out, int out_size, void* d_ws, size_t ws_size,
                              hipStream_t stream) {
    const float* x   = (const float*)d_in[0];
    const float* ef  = (const float*)d_in[1];
    const int*   ei  = (const int*)d_in[2];
    const float* Wq  = (const float*)d_in[3];
    const float* Wk  = (const float*)d_in[4];
    const float* Wv  = (const float*)d_in[5];
    const float* We  = (const float*)d_in[6];
    const float* Wo  = (const float*)d_in[7];
    const float* bo  = (const float*)d_in[8];
    const float* Wg  = (const float*)d_in[9];
    const float* bg  = (const float*)d_in[10];
    const float* l1s = (const float*)d_in[11];
    const float* l1b = (const float*)d_in[12];
    const float* Wf1 = (const float*)d_in[13];
    const float* bf1 = (const float*)d_in[14];
    const float* Wf2 = (const float*)d_in[15];
    const float* bf2 = (const float*)d_in[16];
    const float* l2s = (const float*)d_in[17];
    const float* l2b = (const float*)d_in[18];

    int N = in_sizes[0] / Dm;
    int E = in_sizes[1] / DEe;
    float* out = (float*)d_out;

    char* wp = (char*)d_ws;
    auto alloc = [&](size_t bytes) -> void* {
        void* p = wp;
        wp += (bytes + 255) & ~(size_t)255;
        return p;
    };
    size_t NF = (size_t)N * Dm;
    u16*   xb     = (u16*)alloc(NF * 2);
    u16*   qkvb   = (u16*)alloc((size_t)N * 576 * 2);
    u16*   aggb   = (u16*)alloc(NF * 2);
    float* scb    = (float*)alloc((size_t)E * 8 * 4);
    int*   sbuf   = (int*)  alloc((size_t)E * 4);
    int*   degcur = (int*)  alloc((size_t)2 * N * 4);
    int*   offs   = (int*)  alloc((size_t)(N + 1) * 4);
    u16*   Wqkvt  = (u16*)alloc((size_t)576 * 192 * 2);
    u16*   Wot    = (u16*)alloc((size_t)192 * 192 * 2);
    u16*   Wgt    = (u16*)alloc((size_t)192 * 384 * 2);
    u16*   Wf1t   = (u16*)alloc((size_t)384 * 192 * 2);
    u16*   Wf2t   = (u16*)alloc((size_t)192 * 384 * 2);
    u16*   ff1b   = (u16*)alloc((size_t)N * 384 * 2);
    int* deg = degcur;
    int* cur = degcur + N;
    // aliases (lifetimes disjoint)
    u16* ob = qkvb;                   // qkv dead after agg_fused
    u16* yb = qkvb + (size_t)N * Dm;

    int gm = (N + 63) / 64;

    prep_w<<<dim3(1440), 256, 0, stream>>>(Wq, Wk, Wv, Wo, Wg, Wf1, Wf2,
        Wqkvt, Wot, Wgt, Wf1t, Wf2t);
    xconv<<<dim3((N * Dm / 4 + 255) / 256), 256, 0, stream>>>(x, N * Dm / 4, xb);
    zero_ints<<<dim3((2 * N + 255) / 256), 256, 0, stream>>>(degcur, 2 * N);
    count_deg<<<dim3((E + 255) / 256), 256, 0, stream>>>(ei, E, deg);
    scan_kernel<<<dim3(1), 1024, 0, stream>>>(deg, N, offs);

    // QKV fused: [N,192] @ [192,576] -> qkvb bf16
    gemm_mfma<<<dim3(gm, 3), 256, 0, stream>>>(xb, nullptr, Dm, N, 192, Wqkvt,
        nullptr, qkvb, nullptr, 576, M_NONE, nullptr, nullptr, nullptr, nullptr);

    edge_prep<<<dim3((E + 31) / 32), 256, 0, stream>>>(ei, E, ef, We,
        offs, cur, scb, sbuf);
    agg_fused<<<dim3((N + 3) / 4), 256, 0, stream>>>(qkvb, scb, sbuf, offs, N, aggb);

    // o = agg @ Wo + bo  (bf16)
    gemm_mfma<<<dim3(gm, 1), 256, 0, stream>>>(aggb, nullptr, Dm, N, 192, Wot,
        bo, ob, nullptr, Dm, M_BIAS, nullptr, nullptr, nullptr, nullptr);

    // y = LN1(g*o + (1-g)*x), g = sigmoid(concat(o,x)@Wg+bg)
    gemm_mfma<<<dim3(gm, 1), 256, 0, stream>>>(ob, xb, Dm, N, 384, Wgt,
        bg, yb, nullptr, Dm, M_GATE_LN, ob, xb, l1s, l1b);

    // ff1 = silu(y @ Wf1 + bf1)
    gemm_mfma<<<dim3(gm, 2), 256, 0, stream>>>(yb, nullptr, Dm, N, 192, Wf1t,
        bf1, ff1b, nullptr, 384, M_SILU, nullptr, nullptr, nullptr, nullptr);

    // out = LN2(y + ff1 @ Wf2 + bf2)  (fp32)
    gemm_mfma<<<dim3(gm, 1), 256, 0, stream>>>(ff1b, nullptr, 384, N, 384, Wf2t,
        bf2, nullptr, out, Dm, M_RES_LN, yb, nullptr, l2s, l2b);
}

// Round 4
// 295.243 us; speedup vs baseline: 2.0793x; 1.0426x over previous
//
#include <hip/hip_runtime.h>
#include <cstdint>
#include <cstddef>

#define LOG2E 1.4426950408889634f

constexpr int Dm  = 192;
constexpr int DEe = 96;

typedef unsigned short u16;
typedef __attribute__((ext_vector_type(8))) short short8v;
typedef __attribute__((ext_vector_type(4))) float f32x4;

__device__ __forceinline__ u16 f2bf(float f) {
    uint32_t u = __builtin_bit_cast(uint32_t, f);
    uint32_t r = (u + 0x7FFF + ((u >> 16) & 1)) >> 16;
    return (u16)r;
}
__device__ __forceinline__ float bf2f(u16 h) {
    uint32_t u = ((uint32_t)h) << 16;
    return __builtin_bit_cast(float, u);
}

// ---------------------------------------------------------------- utilities
__global__ void zero_ints(int* __restrict__ p, int n) {
    int i = blockIdx.x * blockDim.x + threadIdx.x;
    if (i < n) p[i] = 0;
}

__global__ void count_deg(const int* __restrict__ ei, int E, int* __restrict__ deg) {
    int e = blockIdx.x * blockDim.x + threadIdx.x;
    if (e < E) atomicAdd(&deg[ei[E + e]], 1);
}

__global__ __launch_bounds__(1024) void scan_kernel(const int* __restrict__ deg, int N,
                                                    int* __restrict__ offs) {
    __shared__ int sp[1024];
    int t = threadIdx.x;
    int per = (N + 1023) >> 10;
    int base = t * per;
    int sum = 0;
    for (int i = 0; i < per; ++i) {
        int idx = base + i;
        if (idx < N) sum += deg[idx];
    }
    sp[t] = sum;
    __syncthreads();
    for (int off = 1; off < 1024; off <<= 1) {
        int v = (t >= off) ? sp[t - off] : 0;
        __syncthreads();
        sp[t] += v;
        __syncthreads();
    }
    int run = sp[t] - sum;
    for (int i = 0; i < per; ++i) {
        int idx = base + i;
        if (idx < N) { offs[idx] = run; run += deg[idx]; }
    }
    if (t == 1023) offs[N] = sp[1023];
}

// fp32 -> bf16 (vectorized float4 -> ushort4)
__global__ void xconv(const float* __restrict__ x, int n4, u16* __restrict__ xb) {
    int i = blockIdx.x * blockDim.x + threadIdx.x;
    if (i >= n4) return;
    float4 v = ((const float4*)x)[i];
    ushort4 o;
    o.x = f2bf(v.x); o.y = f2bf(v.y); o.z = f2bf(v.z); o.w = f2bf(v.w);
    ((ushort4*)xb)[i] = o;
}

// all weight transposes+conversions in one launch. Wt layouts: [Nout][K] bf16.
__global__ void prep_w(const float* __restrict__ Wq, const float* __restrict__ Wk,
                       const float* __restrict__ Wv, const float* __restrict__ Wo,
                       const float* __restrict__ Wg, const float* __restrict__ Wf1,
                       const float* __restrict__ Wf2,
                       u16* __restrict__ Wqkvt, u16* __restrict__ Wot,
                       u16* __restrict__ Wgt, u16* __restrict__ Wf1t,
                       u16* __restrict__ Wf2t) {
    int idx = blockIdx.x * blockDim.x + threadIdx.x;
    if (idx < 110592) {                    // QKV: [576][192]
        int n = idx / 192, k = idx % 192;
        const float* W = n < 192 ? Wq : (n < 384 ? Wk : Wv);
        Wqkvt[idx] = f2bf(W[(size_t)k * 192 + (n % 192)]);
    } else if (idx < 147456) {             // Wo: [192][192]
        int i = idx - 110592;
        int n = i / 192, k = i % 192;
        Wot[i] = f2bf(Wo[(size_t)k * 192 + n]);
    } else if (idx < 221184) {             // Wg: [192][384]
        int i = idx - 147456;
        int n = i / 384, k = i % 384;
        Wgt[i] = f2bf(Wg[(size_t)k * 192 + n]);
    } else if (idx < 294912) {             // Wf1: [384][192]
        int i = idx - 221184;
        int n = i / 192, k = i % 192;
        Wf1t[i] = f2bf(Wf1[(size_t)k * 384 + n]);
    } else if (idx < 368640) {             // Wf2: [192][384]
        int i = idx - 294912;
        int n = i / 384, k = i % 384;
        Wf2t[i] = f2bf(Wf2[(size_t)k * 192 + n]);
    }
}

// ---------------------------------------- edge prep: ef@We + CSR scatter
__global__ __launch_bounds__(256) void edge_prep(
    const int* __restrict__ ei, int E,
    const float* __restrict__ ef, const float* __restrict__ We,
    const int* __restrict__ offs, int* __restrict__ cur,
    float* __restrict__ scb, int* __restrict__ sbuf)
{
    __shared__ float We_s[DEe * 8];
    __shared__ float ef_s[32][100];
    int tid = threadIdx.x;
    for (int i = tid; i < DEe * 8; i += 256) We_s[i] = We[i];
    int e0 = blockIdx.x * 32;
    #pragma unroll
    for (int rep = 0; rep < 3; ++rep) {
        int idx = tid + 256 * rep;
        int el = idx / 24, c4 = idx % 24;
        int e = e0 + el;
        float4 v = make_float4(0.f, 0.f, 0.f, 0.f);
        if (e < E) v = *(const float4*)&ef[(size_t)e * DEe + c4 * 4];
        *(float4*)&ef_s[el][c4 * 4] = v;
    }
    __syncthreads();
    int el = tid >> 3, h = tid & 7;
    int e = e0 + el;
    if (e >= E) return;
    float epj = 0.f;
    #pragma unroll 8
    for (int i = 0; i < DEe; ++i) epj += ef_s[el][i] * We_s[i * 8 + h];

    int lane = tid & 63;
    int pos = 0;
    if (h == 0) {
        int dst = ei[E + e];
        pos = offs[dst] + atomicAdd(&cur[dst], 1);
    }
    pos = __shfl(pos, lane & 56, 64);
    scb[(size_t)pos * 8 + h] = epj * LOG2E;
    if (h == 0) sbuf[pos] = ei[e];   // src
}

// ---------------------------------------- fused score + softmax + PV per node
__global__ __launch_bounds__(256) void agg_fused(
    const u16* __restrict__ qkv, const float* __restrict__ scb,
    const int* __restrict__ sbuf, const int* __restrict__ offs,
    int N, u16* __restrict__ aggb)
{
    int node = blockIdx.x * 4 + (threadIdx.x >> 6);
    if (node >= N) return;
    int lane = threadIdx.x & 63;
    int h = lane >> 3;
    int di = (3 * lane) >> 1;
    int odd = lane & 1;

    const uint32_t* qrow = (const uint32_t*)(qkv + (size_t)node * 576);
    uint32_t qd0 = qrow[di], qd1 = qrow[di + 1];
    float q0, q1, q2;
    if (!odd) { q0 = bf2f(qd0 & 0xffff); q1 = bf2f(qd0 >> 16); q2 = bf2f(qd1 & 0xffff); }
    else      { q0 = bf2f(qd0 >> 16);    q1 = bf2f(qd1 & 0xffff); q2 = bf2f(qd1 >> 16); }

    float den = 0.f, a0 = 0.f, a1 = 0.f, a2 = 0.f;
    int beg = offs[node], end = offs[node + 1];

    uint32_t kd0_n = 0, kd1_n = 0, vd0_n = 0, vd1_n = 0; float ep_n = 0.f;
    if (beg < end) {
        int src = sbuf[beg];
        const uint32_t* kr = (const uint32_t*)(qkv + (size_t)src * 576 + 192);
        kd0_n = kr[di]; kd1_n = kr[di + 1];
        const uint32_t* vr = (const uint32_t*)(qkv + (size_t)src * 576 + 384);
        vd0_n = vr[di]; vd1_n = vr[di + 1];
        ep_n = scb[(size_t)beg * 8 + h];
    }

    for (int idx = beg; idx < end; ++idx) {
        uint32_t kd0 = kd0_n, kd1 = kd1_n, vd0 = vd0_n, vd1 = vd1_n;
        float ep = ep_n;
        if (idx + 1 < end) {
            int src = sbuf[idx + 1];
            const uint32_t* kr = (const uint32_t*)(qkv + (size_t)src * 576 + 192);
            kd0_n = kr[di]; kd1_n = kr[di + 1];
            const uint32_t* vr = (const uint32_t*)(qkv + (size_t)src * 576 + 384);
            vd0_n = vr[di]; vd1_n = vr[di + 1];
            ep_n = scb[(size_t)(idx + 1) * 8 + h];
        }
        float k0, k1, k2, v0, v1, v2;
        if (!odd) {
            k0 = bf2f(kd0 & 0xffff); k1 = bf2f(kd0 >> 16); k2 = bf2f(kd1 & 0xffff);
            v0 = bf2f(vd0 & 0xffff); v1 = bf2f(vd0 >> 16); v2 = bf2f(vd1 & 0xffff);
        } else {
            k0 = bf2f(kd0 >> 16); k1 = bf2f(kd1 & 0xffff); k2 = bf2f(kd1 >> 16);
            v0 = bf2f(vd0 >> 16); v1 = bf2f(vd1 & 0xffff); v2 = bf2f(vd1 >> 16);
        }
        float pd = q0 * k0 + q1 * k1 + q2 * k2;
        pd += __shfl_xor(pd, 1, 64);
        pd += __shfl_xor(pd, 2, 64);
        pd += __shfl_xor(pd, 4, 64);
        float p = exp2f(pd * 0.2944885836f + ep);
        den += p;
        a0 += p * v0; a1 += p * v1; a2 += p * v2;
    }
    float rden = 1.f / (den + 1e-8f);
    u16* og = aggb + (size_t)node * Dm;
    int b0 = 3 * lane;
    og[b0]     = f2bf(a0 * rden);
    og[b0 + 1] = f2bf(a1 * rden);
    og[b0 + 2] = f2bf(a2 * rden);
}

// ---------------------------------------- zero-LDS fragment GEMM: QKV
// C[M,576] = xb[M,192] @ Wqkv; block = 64 rows x 192 cols, 4 waves.
__global__ __launch_bounds__(256) void qkv_gemm(
    const u16* __restrict__ xb, int M,
    const u16* __restrict__ Wt, u16* __restrict__ qkvb)
{
    int tid = threadIdx.x;
    int m0 = blockIdx.x * 64, n0 = blockIdx.y * 192;
    int w = tid >> 6, lane = tid & 63;
    int c16 = lane & 15, hi2 = lane >> 4, kof = hi2 * 8;

    int rcm[4];
    #pragma unroll
    for (int mr = 0; mr < 4; ++mr) {
        int r = m0 + mr * 16 + c16;
        rcm[mr] = r < M ? r : M - 1;
    }

    f32x4 acc[4][3];
    #pragma unroll
    for (int mr = 0; mr < 4; ++mr)
        #pragma unroll
        for (int nr = 0; nr < 3; ++nr) acc[mr][nr] = (f32x4)(0.f);

    #pragma unroll
    for (int ks = 0; ks < 6; ++ks) {
        short8v af[4], bfr[3];
        #pragma unroll
        for (int mr = 0; mr < 4; ++mr)
            af[mr] = *(const short8v*)(xb + (size_t)rcm[mr] * 192 + ks * 32 + kof);
        #pragma unroll
        for (int nr = 0; nr < 3; ++nr)
            bfr[nr] = *(const short8v*)(Wt + (size_t)(n0 + w * 48 + nr * 16 + c16) * 192 + ks * 32 + kof);
        #pragma unroll
        for (int mr = 0; mr < 4; ++mr)
            #pragma unroll
            for (int nr = 0; nr < 3; ++nr)
                acc[mr][nr] = __builtin_amdgcn_mfma_f32_16x16x32_bf16(
                    af[mr], bfr[nr], acc[mr][nr], 0, 0, 0);
    }

    #pragma unroll
    for (int mr = 0; mr < 4; ++mr)
        #pragma unroll
        for (int reg = 0; reg < 4; ++reg) {
            int r = m0 + mr * 16 + hi2 * 4 + reg;
            if (r >= M) continue;
            #pragma unroll
            for (int nr = 0; nr < 3; ++nr)
                qkvb[(size_t)r * 576 + n0 + w * 48 + nr * 16 + c16] =
                    f2bf(acc[mr][nr][reg]);
        }
}

// ---------------------------------------- fused node chain:
// o = agg@Wo+bo; y = LN1(g*o+(1-g)*x), g = sigmoid([o,x]@Wg+bg);
// out = LN2(y + silu(y@Wf1+bf1)@Wf2 + bf2).  64 rows/block, 4 waves.
__global__ __launch_bounds__(256) void chain_fused(
    const u16* __restrict__ aggb, const u16* __restrict__ xb, int M,
    const u16* __restrict__ Wot, const float* __restrict__ bo,
    const u16* __restrict__ Wgt, const float* __restrict__ bg,
    const float* __restrict__ l1s, const float* __restrict__ l1b,
    const u16* __restrict__ Wf1t, const float* __restrict__ bf1,
    const u16* __restrict__ Wf2t, const float* __restrict__ bf2,
    const float* __restrict__ l2s, const float* __restrict__ l2b,
    float* __restrict__ out)
{
    __shared__ __align__(16) short Ybuf[64 * 200];   // o, then y (stride 200)
    __shared__ __align__(16) short Fbuf[64 * 392];   // ff1 (stride 392)
    __shared__ float red[2][4][64];

    int tid = threadIdx.x;
    int m0 = blockIdx.x * 64;
    int w = tid >> 6, lane = tid & 63;
    int c16 = lane & 15, hi2 = lane >> 4, kof = hi2 * 8;

    int rcm[4];
    #pragma unroll
    for (int mr = 0; mr < 4; ++mr) {
        int r = m0 + mr * 16 + c16;
        rcm[mr] = r < M ? r : M - 1;
    }

    // ---- stage0: o = agg @ Wo + bo (no LDS operands)
    f32x4 oacc[4][3];
    #pragma unroll
    for (int mr = 0; mr < 4; ++mr)
        #pragma unroll
        for (int nr = 0; nr < 3; ++nr) oacc[mr][nr] = (f32x4)(0.f);
    #pragma unroll
    for (int ks = 0; ks < 6; ++ks) {
        short8v af[4], bfr[3];
        #pragma unroll
        for (int mr = 0; mr < 4; ++mr)
            af[mr] = *(const short8v*)(aggb + (size_t)rcm[mr] * 192 + ks * 32 + kof);
        #pragma unroll
        for (int nr = 0; nr < 3; ++nr)
            bfr[nr] = *(const short8v*)(Wot + (size_t)(w * 48 + nr * 16 + c16) * 192 + ks * 32 + kof);
        #pragma unroll
        for (int mr = 0; mr < 4; ++mr)
            #pragma unroll
            for (int nr = 0; nr < 3; ++nr)
                oacc[mr][nr] = __builtin_amdgcn_mfma_f32_16x16x32_bf16(
                    af[mr], bfr[nr], oacc[mr][nr], 0, 0, 0);
    }
    #pragma unroll
    for (int nr = 0; nr < 3; ++nr) {
        int col = w * 48 + nr * 16 + c16;
        float b = bo[col];
        #pragma unroll
        for (int mr = 0; mr < 4; ++mr)
            #pragma unroll
            for (int reg = 0; reg < 4; ++reg) {
                oacc[mr][nr][reg] += b;
                int row = mr * 16 + hi2 * 4 + reg;
                Ybuf[row * 200 + col] = (short)f2bf(oacc[mr][nr][reg]);
            }
    }
    __syncthreads();

    // ---- stage1: z = [o,x] @ Wg + bg; gate; LN1 -> y
    f32x4 zacc[4][3];
    #pragma unroll
    for (int mr = 0; mr < 4; ++mr)
        #pragma unroll
        for (int nr = 0; nr < 3; ++nr) zacc[mr][nr] = (f32x4)(0.f);
    #pragma unroll
    for (int ks = 0; ks < 6; ++ks) {          // o half (from LDS)
        short8v af[4], bfr[3];
        #pragma unroll
        for (int mr = 0; mr < 4; ++mr)
            af[mr] = *(const short8v*)&Ybuf[(mr * 16 + c16) * 200 + ks * 32 + kof];
        #pragma unroll
        for (int nr = 0; nr < 3; ++nr)
            bfr[nr] = *(const short8v*)(Wgt + (size_t)(w * 48 + nr * 16 + c16) * 384 + ks * 32 + kof);
        #pragma unroll
        for (int mr = 0; mr < 4; ++mr)
            #pragma unroll
            for (int nr = 0; nr < 3; ++nr)
                zacc[mr][nr] = __builtin_amdgcn_mfma_f32_16x16x32_bf16(
                    af[mr], bfr[nr], zacc[mr][nr], 0, 0, 0);
    }
    #pragma unroll
    for (int ks = 6; ks < 12; ++ks) {         // x half (from global)
        short8v af[4], bfr[3];
        #pragma unroll
        for (int mr = 0; mr < 4; ++mr)
            af[mr] = *(const short8v*)(xb + (size_t)rcm[mr] * 192 + (ks - 6) * 32 + kof);
        #pragma unroll
        for (int nr = 0; nr < 3; ++nr)
            bfr[nr] = *(const short8v*)(Wgt + (size_t)(w * 48 + nr * 16 + c16) * 384 + ks * 32 + kof);
        #pragma unroll
        for (int mr = 0; mr < 4; ++mr)
            #pragma unroll
            for (int nr = 0; nr < 3; ++nr)
                zacc[mr][nr] = __builtin_amdgcn_mfma_f32_16x16x32_bf16(
                    af[mr], bfr[nr], zacc[mr][nr], 0, 0, 0);
    }
    float s1p[4][4], s2p[4][4];
    #pragma unroll
    for (int mr = 0; mr < 4; ++mr)
        #pragma unroll
        for (int reg = 0; reg < 4; ++reg) {
            int gr = m0 + mr * 16 + hi2 * 4 + reg;
            int rcR = gr < M ? gr : M - 1;
            float s1 = 0.f, s2 = 0.f;
            #pragma unroll
            for (int nr = 0; nr < 3; ++nr) {
                int col = w * 48 + nr * 16 + c16;
                float z = zacc[mr][nr][reg] + bg[col];
                float g = 1.f / (1.f + expf(-z));
                float xv = bf2f(xb[(size_t)rcR * 192 + col]);
                float val = g * oacc[mr][nr][reg] + (1.f - g) * xv;
                zacc[mr][nr][reg] = val;
                s1 += val; s2 += val * val;
            }
            #pragma unroll
            for (int mS = 1; mS < 16; mS <<= 1) {
                s1 += __shfl_xor(s1, mS, 64);
                s2 += __shfl_xor(s2, mS, 64);
            }
            s1p[mr][reg] = s1; s2p[mr][reg] = s2;
        }
    if (c16 == 0) {
        #pragma unroll
        for (int mr = 0; mr < 4; ++mr)
            #pragma unroll
            for (int reg = 0; reg < 4; ++reg) {
                int rowIdx = mr * 16 + hi2 * 4 + reg;
                red[0][w][rowIdx] = s1p[mr][reg];
                red[1][w][rowIdx] = s2p[mr][reg];
            }
    }
    __syncthreads();   // also guarantees all Ybuf o-reads are done
    #pragma unroll
    for (int mr = 0; mr < 4; ++mr)
        #pragma unroll
        for (int reg = 0; reg < 4; ++reg) {
            int rowIdx = mr * 16 + hi2 * 4 + reg;
            float S1 = red[0][0][rowIdx] + red[0][1][rowIdx] + red[0][2][rowIdx] + red[0][3][rowIdx];
            float S2 = red[1][0][rowIdx] + red[1][1][rowIdx] + red[1][2][rowIdx] + red[1][3][rowIdx];
            float mean = S1 * (1.f / 192.f);
            float var  = S2 * (1.f / 192.f) - mean * mean;
            float inv  = rsqrtf(var + 1e-5f);
            #pragma unroll
            for (int nr = 0; nr < 3; ++nr) {
                int col = w * 48 + nr * 16 + c16;
                float yv = (zacc[mr][nr][reg] - mean) * inv * l1s[col] + l1b[col];
                zacc[mr][nr][reg] = yv;                    // keep y in regs too
                Ybuf[rowIdx * 200 + col] = (short)f2bf(yv);
            }
        }
    __syncthreads();

    // ---- stage2: t = silu(y @ Wf1 + bf1), cols w*96 + nr*16, nr<6
    f32x4 tacc[4][6];
    #pragma unroll
    for (int mr = 0; mr < 4; ++mr)
        #pragma unroll
        for (int nr = 0; nr < 6; ++nr) tacc[mr][nr] = (f32x4)(0.f);
    #pragma unroll
    for (int ks = 0; ks < 6; ++ks) {
        short8v af[4], bfr[6];
        #pragma unroll
        for (int mr = 0; mr < 4; ++mr)
            af[mr] = *(const short8v*)&Ybuf[(mr * 16 + c16) * 200 + ks * 32 + kof];
        #pragma unroll
        for (int nr = 0; nr < 6; ++nr)
            bfr[nr] = *(const short8v*)(Wf1t + (size_t)(w * 96 + nr * 16 + c16) * 192 + ks * 32 + kof);
        #pragma unroll
        for (int mr = 0; mr < 4; ++mr)
            #pragma unroll
            for (int nr = 0; nr < 6; ++nr)
                tacc[mr][nr] = __builtin_amdgcn_mfma_f32_16x16x32_bf16(
                    af[mr], bfr[nr], tacc[mr][nr], 0, 0, 0);
    }
    #pragma unroll
    for (int nr = 0; nr < 6; ++nr) {
        int col = w * 96 + nr * 16 + c16;
        float b = bf1[col];
        #pragma unroll
        for (int mr = 0; mr < 4; ++mr)
            #pragma unroll
            for (int reg = 0; reg < 4; ++reg) {
                float z = tacc[mr][nr][reg] + b;
                float t = z / (1.f + expf(-z));
                int row = mr * 16 + hi2 * 4 + reg;
                Fbuf[row * 392 + col] = (short)f2bf(t);
            }
    }
    __syncthreads();

    // ---- stage3: out = LN2(y + t @ Wf2 + bf2)
    f32x4 facc[4][3];
    #pragma unroll
    for (int mr = 0; mr < 4; ++mr)
        #pragma unroll
        for (int nr = 0; nr < 3; ++nr) facc[mr][nr] = (f32x4)(0.f);
    #pragma unroll
    for (int ks = 0; ks < 12; ++ks) {
        short8v af[4], bfr[3];
        #pragma unroll
        for (int mr = 0; mr < 4; ++mr)
            af[mr] = *(const short8v*)&Fbuf[(mr * 16 + c16) * 392 + ks * 32 + kof];
        #pragma unroll
        for (int nr = 0; nr < 3; ++nr)
            bfr[nr] = *(const short8v*)(Wf2t + (size_t)(w * 48 + nr * 16 + c16) * 384 + ks * 32 + kof);
        #pragma unroll
        for (int mr = 0; mr < 4; ++mr)
            #pragma unroll
            for (int nr = 0; nr < 3; ++nr)
                facc[mr][nr] = __builtin_amdgcn_mfma_f32_16x16x32_bf16(
                    af[mr], bfr[nr], facc[mr][nr], 0, 0, 0);
    }
    #pragma unroll
    for (int mr = 0; mr < 4; ++mr)
        #pragma unroll
        for (int reg = 0; reg < 4; ++reg) {
            int rowIdx = mr * 16 + hi2 * 4 + reg;
            float s1 = 0.f, s2 = 0.f;
            #pragma unroll
            for (int nr = 0; nr < 3; ++nr) {
                int col = w * 48 + nr * 16 + c16;
                float val = facc[mr][nr][reg] + bf2[col] + bf2f((u16)Ybuf[rowIdx * 200 + col]);
                facc[mr][nr][reg] = val;
                s1 += val; s2 += val * val;
            }
            #pragma unroll
            for (int mS = 1; mS < 16; mS <<= 1) {
                s1 += __shfl_xor(s1, mS, 64);
                s2 += __shfl_xor(s2, mS, 64);
            }
            s1p[mr][reg] = s1; s2p[mr][reg] = s2;
        }
    if (c16 == 0) {
        #pragma unroll
        for (int mr = 0; mr < 4; ++mr)
            #pragma unroll
            for (int reg = 0; reg < 4; ++reg) {
                int rowIdx = mr * 16 + hi2 * 4 + reg;
                red[0][w][rowIdx] = s1p[mr][reg];
                red[1][w][rowIdx] = s2p[mr][reg];
            }
    }
    __syncthreads();
    #pragma unroll
    for (int mr = 0; mr < 4; ++mr)
        #pragma unroll
        for (int reg = 0; reg < 4; ++reg) {
            int rowIdx = mr * 16 + hi2 * 4 + reg;
            int r = m0 + rowIdx;
            if (r >= M) continue;
            float S1 = red[0][0][rowIdx] + red[0][1][rowIdx] + red[0][2][rowIdx] + red[0][3][rowIdx];
            float S2 = red[1][0][rowIdx] + red[1][1][rowIdx] + red[1][2][rowIdx] + red[1][3][rowIdx];
            float mean = S1 * (1.f / 192.f);
            float var  = S2 * (1.f / 192.f) - mean * mean;
            float inv  = rsqrtf(var + 1e-5f);
            #pragma unroll
            for (int nr = 0; nr < 3; ++nr) {
                int col = w * 48 + nr * 16 + c16;
                out[(size_t)r * 192 + col] =
                    (facc[mr][nr][reg] - mean) * inv * l2s[col] + l2b[col];
            }
        }
}

// ---------------------------------------------------------------- launcher
extern "C" void kernel_launch(void* const* d_in, const int* in_sizes, int n_in,
                              void* d_out, int out_size, void* d_ws, size_t ws_size,
                              hipStream_t stream) {
    const float* x   = (const float*)d_in[0];
    const float* ef  = (const float*)d_in[1];
    const int*   ei  = (const int*)d_in[2];
    const float* Wq  = (const float*)d_in[3];
    const float* Wk  = (const float*)d_in[4];
    const float* Wv  = (const float*)d_in[5];
    const float* We  = (const float*)d_in[6];
    const float* Wo  = (const float*)d_in[7];
    const float* bo  = (const float*)d_in[8];
    const float* Wg  = (const float*)d_in[9];
    const float* bg  = (const float*)d_in[10];
    const float* l1s = (const float*)d_in[11];
    const float* l1b = (const float*)d_in[12];
    const float* Wf1 = (const float*)d_in[13];
    const float* bf1 = (const float*)d_in[14];
    const float* Wf2 = (const float*)d_in[15];
    const float* bf2 = (const float*)d_in[16];
    const float* l2s = (const float*)d_in[17];
    const float* l2b = (const float*)d_in[18];

    int N = in_sizes[0] / Dm;
    int E = in_sizes[1] / DEe;
    float* out = (float*)d_out;

    char* wp = (char*)d_ws;
    auto alloc = [&](size_t bytes) -> void* {
        void* p = wp;
        wp += (bytes + 255) & ~(size_t)255;
        return p;
    };
    size_t NF = (size_t)N * Dm;
    u16*   xb     = (u16*)alloc(NF * 2);
    u16*   qkvb   = (u16*)alloc((size_t)N * 576 * 2);
    u16*   aggb   = (u16*)alloc(NF * 2);
    float* scb    = (float*)alloc((size_t)E * 8 * 4);
    int*   sbuf   = (int*)  alloc((size_t)E * 4);
    int*   degcur = (int*)  alloc((size_t)2 * N * 4);
    int*   offs   = (int*)  alloc((size_t)(N + 1) * 4);
    u16*   Wqkvt  = (u16*)alloc((size_t)576 * 192 * 2);
    u16*   Wot    = (u16*)alloc((size_t)192 * 192 * 2);
    u16*   Wgt    = (u16*)alloc((size_t)192 * 384 * 2);
    u16*   Wf1t   = (u16*)alloc((size_t)384 * 192 * 2);
    u16*   Wf2t   = (u16*)alloc((size_t)192 * 384 * 2);
    int* deg = degcur;
    int* cur = degcur + N;

    int gm = (N + 63) / 64;

    prep_w<<<dim3(1440), 256, 0, stream>>>(Wq, Wk, Wv, Wo, Wg, Wf1, Wf2,
        Wqkvt, Wot, Wgt, Wf1t, Wf2t);
    xconv<<<dim3((N * Dm / 4 + 255) / 256), 256, 0, stream>>>(x, N * Dm / 4, xb);
    zero_ints<<<dim3((2 * N + 255) / 256), 256, 0, stream>>>(degcur, 2 * N);
    count_deg<<<dim3((E + 255) / 256), 256, 0, stream>>>(ei, E, deg);
    scan_kernel<<<dim3(1), 1024, 0, stream>>>(deg, N, offs);

    qkv_gemm<<<dim3(gm, 3), 256, 0, stream>>>(xb, N, Wqkvt, qkvb);

    edge_prep<<<dim3((E + 31) / 32), 256, 0, stream>>>(ei, E, ef, We,
        offs, cur, scb, sbuf);
    agg_fused<<<dim3((N + 3) / 4), 256, 0, stream>>>(qkvb, scb, sbuf, offs, N, aggb);

    chain_fused<<<dim3(gm), 256, 0, stream>>>(aggb, xb, N,
        Wot, bo, Wgt, bg, l1s, l1b, Wf1t, bf1, Wf2t, bf2, l2s, l2b, out);
}